// Round 3
// baseline (249.556 us; speedup 1.0000x reference)
//
#include <hip/hip_runtime.h>
#include <hip/hip_bf16.h>

// One-hot: label (H*W int32) -> out (N, H, W) float32.
// Memory-bound, write-dominated (64 MiB read + 512 MiB write).
// Each thread loads 8 labels (2x int4) and streams two 16B vectors per class
// plane via non-temporal stores (write-once output -> bypass cache allocate).

typedef float v4f __attribute__((ext_vector_type(4)));  // clang vector: OK for nontemporal builtin

__global__ void __launch_bounds__(256) get_one_hot_59442347376951_kernel(
    const int* __restrict__ label, float* __restrict__ out,
    int total /* H*W */, int N) {
    long long i = ((long long)blockIdx.x * blockDim.x + threadIdx.x) * 8;
    if (i >= total) return;

    int4 la = *reinterpret_cast<const int4*>(label + i);
    int4 lb = *reinterpret_cast<const int4*>(label + i + 4);

    for (int n = 0; n < N; ++n) {
        v4f va, vb;
        va.x = (la.x == n) ? 1.0f : 0.0f;
        va.y = (la.y == n) ? 1.0f : 0.0f;
        va.z = (la.z == n) ? 1.0f : 0.0f;
        va.w = (la.w == n) ? 1.0f : 0.0f;
        vb.x = (lb.x == n) ? 1.0f : 0.0f;
        vb.y = (lb.y == n) ? 1.0f : 0.0f;
        vb.z = (lb.z == n) ? 1.0f : 0.0f;
        vb.w = (lb.w == n) ? 1.0f : 0.0f;
        v4f* p = reinterpret_cast<v4f*>(out + (long long)n * total + i);
        __builtin_nontemporal_store(va, p);
        __builtin_nontemporal_store(vb, p + 1);
    }
}

extern "C" void kernel_launch(void* const* d_in, const int* in_sizes, int n_in,
                              void* d_out, int out_size, void* d_ws, size_t ws_size,
                              hipStream_t stream) {
    const int* label = (const int*)d_in[0];
    float* out = (float*)d_out;

    int total = in_sizes[0];          // H*W = 16,777,216
    int N = out_size / total;         // 8

    int threads = total / 8;          // total divisible by 8
    int block = 256;
    int grid = (threads + block - 1) / block;

    get_one_hot_59442347376951_kernel<<<grid, block, 0, stream>>>(label, out, total, N);
}

// Round 4
// 145.743 us; speedup vs baseline: 1.7123x; 1.7123x over previous
//
#include <hip/hip_runtime.h>
#include <hip/hip_bf16.h>

// One-hot: label (H*W int32) -> out (N, H, W) float32.
// Memory-bound, write-dominated (64 MiB read + 512 MiB write ideal traffic).
//
// Structure: one output plane per blockIdx.y. Each block's stores form a
// single contiguous write stream (fillBuffer-like, which achieves ~84% of
// HBM peak on this chip), instead of round-robining 8 plane-streams per
// wave at 1 KiB granularity (R1, 4.6 TB/s). Label re-reads across the 8
// y-passes are absorbed by the 256 MiB L3 (label array = 64 MiB).
//
// R3 lesson: do NOT use non-temporal stores for dense streaming fp32 writes
// on gfx950 — bypassing L2 write-combining halves effective write BW.
__global__ void __launch_bounds__(256) get_one_hot_59442347376951_kernel(
    const int* __restrict__ label, float* __restrict__ out,
    int total /* H*W */) {
    int i = (blockIdx.x * 256 + threadIdx.x) * 4;
    int n = blockIdx.y;  // class plane (wave-uniform)

    int4 lab = *reinterpret_cast<const int4*>(label + i);

    float4 v;
    v.x = (lab.x == n) ? 1.0f : 0.0f;
    v.y = (lab.y == n) ? 1.0f : 0.0f;
    v.z = (lab.z == n) ? 1.0f : 0.0f;
    v.w = (lab.w == n) ? 1.0f : 0.0f;

    *reinterpret_cast<float4*>(out + (long long)n * total + i) = v;
}

extern "C" void kernel_launch(void* const* d_in, const int* in_sizes, int n_in,
                              void* d_out, int out_size, void* d_ws, size_t ws_size,
                              hipStream_t stream) {
    const int* label = (const int*)d_in[0];
    float* out = (float*)d_out;

    int total = in_sizes[0];          // H*W = 16,777,216
    int N = out_size / total;         // 8

    dim3 block(256);
    dim3 grid(total / (4 * 256), N);  // 16384 x 8

    get_one_hot_59442347376951_kernel<<<grid, block, 0, stream>>>(label, out, total);
}